// Round 4
// baseline (161.853 us; speedup 1.0000x reference)
//
#include <hip/hip_runtime.h>

typedef _Float16 f16;
typedef _Float16 f16x8 __attribute__((ext_vector_type(8)));
typedef float    f32x16 __attribute__((ext_vector_type(16)));

#define NV      2000
#define RR      128
#define KM1     30
#define KKOUT   31
#define NQ      900          // KM1*KM1
#define QQ      961          // KKOUT*KKOUT
#define COV_OFF 62000        // NV*KKOUT

// ws layout:
//   B5 at 0: [qt(29)][kz(4)][stage t(16)][slot(9)][1KB frag] = 17,104,896 B
//     stage (qt,kz,t) holds i_a = kz*16+t (slots 0..7-kz, s=kz..7) then
//     i_b = (7-kz)*16+t (slots 8-kz..8, s=7-kz..7); frag: lane(kq,l31) elem d
//     = Bs[i, j=s*16+kq*8+d, q=qt*32+l31] (f16), zero for j<i, diag 1x.
//   Xh at B5_BYTES: f16 X^T [v 0..2047][r 0..127]
#define B5_BYTES 17104896
#define XH_BYTES 524288

#define PERM_BLKS  3840
#define XC1_BLKS   128
#define ZERO_BLKS  1877
#define MEAN_BLKS  248
#define PREP_GRID  (PERM_BLKS + XC1_BLKS + ZERO_BLKS + MEAN_BLKS)

// ---------------------------------------------------------------------------
// Fused prep: symmetrize+permute Cov -> B5; Xh cast; zero cov + 0.5 diag;
// exact fp32 mean. Roles by blockIdx range.  (unchanged this round)
// ---------------------------------------------------------------------------
__global__ void prep_kernel(const float* __restrict__ Xi,
                            const float* __restrict__ Wm,
                            const float* __restrict__ cov,
                            const float* __restrict__ Cmu,
                            f16* __restrict__ B5,
                            f16* __restrict__ Xh,
                            float* __restrict__ outm,
                            float* __restrict__ oc) {
    __shared__ float rowS[3840];
    int b = blockIdx.x, tid = threadIdx.x;
    if (b < PERM_BLKS) {
        int i = b / 30, k = b - i * 30;
        int g = i >> 4;
        int j0 = g << 4;
        int W = 128 - j0;
        int lo = (i - j0) * 30;                   // rowS[0,lo) = 0 (j<i pad)
        const float* src = cov + (size_t)b * 3840 + j0 * 30;
        for (int t = tid; t < W * 30; t += 256)
            rowS[t] = (t >= lo) ? src[t] : 0.f;
        __syncthreads();
        // symmetrize: rowS[(j-j0)*30+l] += C[(j*30+k),(i*30+l)], j in (i,128)
        int n2 = (127 - i) * 15;                  // float2 pairs
        for (int idx = tid; idx < n2; idx += 256) {
            int j = i + 1 + idx / 15;
            int p = idx - (j - i - 1) * 15;
            const float2 v2 = *(const float2*)(cov + (size_t)(j * 30 + k) * 3840 + i * 30 + 2 * p);
            rowS[(j - j0) * 30 + 2 * p]     += v2.x;
            rowS[(j - j0) * 30 + 2 * p + 1] += v2.y;
        }
        __syncthreads();
        int t_st = i & 15;
        int nOct = W >> 3;
        for (int it = tid; it < nOct * 30; it += 256) {
            int oct = it / 30, l = it - oct * 30;
            int j = j0 + oct * 8;
            int s = j >> 4, kq = (j >> 3) & 1;
            int q = k * 30 + l, qt = q >> 5, l31 = q & 31;
            int kz, slot;
            if (g < 4) { kz = g;     slot = s - g; }
            else       { kz = 7 - g; slot = s + 1; }
            f16 vals[8];
#pragma unroll
            for (int d = 0; d < 8; ++d) vals[d] = (f16)rowS[(j + d - j0) * 30 + l];
            f16* dst = B5 + ((((size_t)(qt * 4 + kz) * 16 + t_st) * 9 + slot) << 9)
                          + (kq * 32 + l31) * 8;
            *(uint4*)dst = *(uint4*)vals;
        }
        return;
    }
    b -= PERM_BLKS;
    if (b < XC1_BLKS) {                           // Xh [v][r]
        int t = b * 256 + tid;
        int v = t & 2047, rc = t >> 11;
        f16 vals[8];
#pragma unroll
        for (int d = 0; d < 8; ++d) {
            float x = (v < NV) ? Xi[(rc * 8 + d) * NV + v] : 0.f;
            vals[d] = (f16)x;
        }
        *(uint4*)(Xh + (size_t)v * 128 + rc * 8) = *(uint4*)vals;
        return;
    }
    b -= XC1_BLKS;
    if (b < ZERO_BLKS) {
        size_t idx = ((size_t)b * 256 + tid) * 4;
        if (idx < (size_t)NV * QQ) {
            unsigned rem = (unsigned)(idx % QQ);
            float4 zv;
            zv.x = (rem == 0u)   ? 0.5f : 0.f;
            zv.y = (rem == 960u) ? 0.5f : 0.f;
            zv.z = (rem == 959u) ? 0.5f : 0.f;
            zv.w = (rem == 958u) ? 0.5f : 0.f;
            *(float4*)(oc + idx) = zv;
        }
        return;
    }
    b -= ZERO_BLKS;
    int t2 = b * 256 + tid;
    int c = t2 >> 11, v = t2 & 2047;
    if (v >= NV || c >= KKOUT) return;
    if (c == 0) { outm[(size_t)v * KKOUT] = Cmu[v]; return; }
    float acc = 0.f;
    const float* w = Wm + (c - 1);
#pragma unroll 8
    for (int i = 0; i < RR; ++i)
        acc = fmaf(Xi[i * NV + v], w[i * KM1], acc);
    outm[(size_t)v * KKOUT + c] = acc;
}

// ---------------------------------------------------------------------------
// load the 9 slot-fragments of one stage (this lane's 16B of each 1KB frag)
// ---------------------------------------------------------------------------
__device__ __forceinline__ void load9(f16x8 (&b)[9], const f16* p) {
#pragma unroll
    for (int m = 0; m < 9; ++m)
        b[m] = *(const f16x8*)(p + m * 512);
}

// ---------------------------------------------------------------------------
// one stage of one kz-section: 9 slots x 2 fm MFMAs.  KZ, T compile-time.
// xj[u] holds x[v, u*16 + kq*8 + d] for s=u.
// role-A slots m: s = KZ+m, scalar xA = x[v, KZ*16+T];
// role-B slots m2: s = 7-KZ+m2, scalar xB = x[v, (7-KZ)*16+T].
// ---------------------------------------------------------------------------
template<int KZ, int T>
__device__ __forceinline__ void stage_compute(int l31,
                                              const f16x8 (&bv)[9],
                                              const f16x8 (&xj)[2][8],
                                              f32x16 (&acc)[2]) {
    constexpr int NA = 8 - KZ, NB = 1 + KZ;
    const int srcl = l31 + ((T >> 3) << 5);
    f16 xA[2], xB[2];
#pragma unroll
    for (int fm = 0; fm < 2; ++fm) {
        unsigned short ha = __builtin_bit_cast(unsigned short, (f16)xj[fm][KZ][T & 7]);
        unsigned short hb = __builtin_bit_cast(unsigned short, (f16)xj[fm][7 - KZ][T & 7]);
        int pa = __shfl((int)ha, srcl, 64);
        int pb = __shfl((int)hb, srcl, 64);
        xA[fm] = __builtin_bit_cast(f16, (unsigned short)pa);
        xB[fm] = __builtin_bit_cast(f16, (unsigned short)pb);
    }
#pragma unroll
    for (int m = 0; m < NA; ++m)
#pragma unroll
        for (int fm = 0; fm < 2; ++fm)
            acc[fm] = __builtin_amdgcn_mfma_f32_32x32x16_f16(xj[fm][KZ + m] * xA[fm], bv[m], acc[fm], 0, 0, 0);
#pragma unroll
    for (int m2 = 0; m2 < NB; ++m2)
#pragma unroll
        for (int fm = 0; fm < 2; ++fm)
            acc[fm] = __builtin_amdgcn_mfma_f32_32x32x16_f16(xj[fm][7 - KZ + m2] * xB[fm], bv[NA + m2], acc[fm], 0, 0, 0);
}

// ---------------------------------------------------------------------------
// Stage recursion: 32 local stages, 3 rolling buffers (all indices static ->
// registers, rule #20). At stage ST: issue loads for ST+2 into buf[(ST+2)%3],
// compute buf[ST%3]. Outstanding = 2 stages (18 loads) -> ~400cy cover.
// Section = KZH*2 + (ST>>4); local t = ST&15.
// ---------------------------------------------------------------------------
template<int KZH, int ST>
struct Stage {
    static __device__ __forceinline__ void run(const f16* gs, f16x8 (&buf)[3][9],
                                               const f16x8 (&xj)[2][8],
                                               f32x16 (&acc)[2], int l31) {
        if constexpr (ST + 2 < 32)
            load9(buf[(ST + 2) % 3], gs + (size_t)(ST + 2) * 4608);
        stage_compute<KZH * 2 + (ST >> 4), ST & 15>(l31, buf[ST % 3], xj, acc);
        Stage<KZH, ST + 1>::run(gs, buf, xj, acc, l31);
    }
};
template<int KZH>
struct Stage<KZH, 32> {
    static __device__ __forceinline__ void run(const f16*, f16x8 (&)[3][9],
                                               const f16x8 (&)[2][8],
                                               f32x16 (&)[2], int) {}
};

// ---------------------------------------------------------------------------
// Half-kz GEMM. Grid 464 = 29 qt x 8 y x 2 half; block = 4 waves x (64v x
// 32q), fm=2 -> 256 v per block. Each block does ONE kz-section pair
// (h=0: sections {0,1} = i in {0..31}u{96..127}; h=1: {2,3} = {32..95});
// the two halves' partial sums combine via atomicAdd onto prep's zero-init.
// 2 blocks/CU -> 2 waves/SIMD TLP (the R3 lesson: 1 wave/SIMD exposed all
// latency) + depth-2 register prefetch (~400cy) together cover ~HBM latency.
// No LDS, no barriers: B read global->VGPR (lane*16B of each 1KB frag,
// coalesced 1KB/wave; waves share via L1/L2).
// XCD map: p=(bid&7)*58+(bid>>3): contiguous ~3.6-qt span per XCD (~2.1MB
// B working set, L2-resident).
// Regs: xj 64 + buf 108 + acc 32 + addr ~20 = ~225 < 256 cap of (256,2).
// ---------------------------------------------------------------------------
__launch_bounds__(256, 2)
__global__ void gemm7_kernel(const f16* __restrict__ B5,
                             const f16* __restrict__ Xh,
                             float* __restrict__ out_cov) {
    const int bid = blockIdx.x;
    const int p = (bid & 7) * 58 + (bid >> 3);   // 0..463
    const int qt = p >> 4;                        // 0..28
    const int r  = p & 15;
    const int y = r >> 1, h = r & 1;              // y 0..7, half 0..1
    const int tid = threadIdx.x, lane = tid & 63, w = tid >> 6;
    const int l31 = lane & 31, kq = lane >> 5;
    const int v0 = y * 256 + w * 64;
    const int vr = v0 + l31;

    // xj[fm][u]: x[vr+fm*32, u*16 + kq*8 + d], full s range
    f16x8 xj[2][8];
#pragma unroll
    for (int fm = 0; fm < 2; ++fm)
#pragma unroll
        for (int u = 0; u < 8; ++u)
            xj[fm][u] = *(const f16x8*)(Xh + (size_t)(vr + fm * 32) * 128 + u * 16 + kq * 8);

    const f16* gbase = B5 + ((size_t)qt * 64 + (size_t)h * 32) * 4608 + lane * 8;

    f16x8 buf[3][9];
    load9(buf[0], gbase);                         // local stage 0
    load9(buf[1], gbase + 4608);                  // local stage 1

    f32x16 acc[2] = {};
    if (h == 0) Stage<0, 0>::run(gbase, buf, xj, acc, l31);
    else        Stage<1, 0>::run(gbase, buf, xj, acc, l31);

    // epilogue: 2-way partial sums -> atomicAdd onto zero-initialized cov.
    // C/D: col=l31 (q), row = 4*kq + (r&3) + 8*(r>>2) within fm's 32-v group.
    const int q = qt * 32 + l31;
    if (q >= NQ) return;
    const int kk = q / 30, ll = q - kk * 30;
    float* cb = out_cov + (kk + 1) * KKOUT + (ll + 1);
#pragma unroll
    for (int fm = 0; fm < 2; ++fm) {
        int vb = v0 + fm * 32 + 4 * kq;
#pragma unroll
        for (int rr = 0; rr < 16; ++rr) {
            int v = vb + (rr & 3) + 8 * (rr >> 2);
            if (v < NV) atomicAdd(cb + (size_t)v * QQ, acc[fm][rr]);
        }
    }
}

// ---------------------------------------------------------------------------
extern "C" void kernel_launch(void* const* d_in, const int* in_sizes, int n_in,
                              void* d_out, int out_size, void* d_ws, size_t ws_size,
                              hipStream_t stream) {
    const float* Xi  = (const float*)d_in[0];   // (128, 2000)
    const float* Wm  = (const float*)d_in[1];   // (3840, 1)
    const float* Cov = (const float*)d_in[2];   // (3840, 3840)
    const float* Cmu = (const float*)d_in[3];   // (2000, 1)
    float* out      = (float*)d_out;
    float* out_mean = out;                       // (2000, 31)
    float* out_cov  = out + COV_OFF;             // (2000, 31, 31)
    f16* B5 = (f16*)d_ws;
    f16* Xh = (f16*)((char*)d_ws + B5_BYTES);

    prep_kernel <<<PREP_GRID, 256, 0, stream>>>(Xi, Wm, Cov, Cmu, B5, Xh,
                                                out_mean, out_cov);
    gemm7_kernel<<<464, 256, 0, stream>>>(B5, Xh, out_cov);
}

// Round 6
// 156.848 us; speedup vs baseline: 1.0319x; 1.0319x over previous
//
#include <hip/hip_runtime.h>

typedef _Float16 f16;
typedef _Float16 f16x8 __attribute__((ext_vector_type(8)));
typedef float    f32x16 __attribute__((ext_vector_type(16)));

#define NV      2000
#define RR      128
#define KM1     30
#define KKOUT   31
#define NQ      900          // KM1*KM1
#define QQ      961          // KKOUT*KKOUT
#define COV_OFF 62000        // NV*KKOUT

// ws layout:
//   B5 at 0: [qt(29)][kz(4)][stage t(16)][slot(9)][1KB frag] = 17,104,896 B
//     stage (qt,kz,t) holds i_a = kz*16+t (slots 0..7-kz, s=kz..7) then
//     i_b = (7-kz)*16+t (slots 8-kz..8, s=7-kz..7); frag: lane(kq,l31) elem d
//     = Bs[i, j=s*16+kq*8+d, q=qt*32+l31] (f16), zero for j<i, diag 1x.
//   Xh at B5_BYTES: f16 X^T [v 0..2047][r 0..127]
#define B5_BYTES 17104896
#define XH_BYTES 524288

#define PERM_BLKS  3840
#define XC1_BLKS   128
#define ZERO_BLKS  1877
#define MEAN_BLKS  248
#define PREP_GRID  (PERM_BLKS + XC1_BLKS + ZERO_BLKS + MEAN_BLKS)

// ---------------------------------------------------------------------------
// Fused prep: symmetrize+permute Cov -> B5; Xh cast; zero cov + 0.5 diag;
// exact fp32 mean. Roles by blockIdx range.  (unchanged this round)
// ---------------------------------------------------------------------------
__global__ void prep_kernel(const float* __restrict__ Xi,
                            const float* __restrict__ Wm,
                            const float* __restrict__ cov,
                            const float* __restrict__ Cmu,
                            f16* __restrict__ B5,
                            f16* __restrict__ Xh,
                            float* __restrict__ outm,
                            float* __restrict__ oc) {
    __shared__ float rowS[3840];
    int b = blockIdx.x, tid = threadIdx.x;
    if (b < PERM_BLKS) {
        int i = b / 30, k = b - i * 30;
        int g = i >> 4;
        int j0 = g << 4;
        int W = 128 - j0;
        int lo = (i - j0) * 30;                   // rowS[0,lo) = 0 (j<i pad)
        const float* src = cov + (size_t)b * 3840 + j0 * 30;
        for (int t = tid; t < W * 30; t += 256)
            rowS[t] = (t >= lo) ? src[t] : 0.f;
        __syncthreads();
        // symmetrize: rowS[(j-j0)*30+l] += C[(j*30+k),(i*30+l)], j in (i,128)
        int n2 = (127 - i) * 15;                  // float2 pairs
        for (int idx = tid; idx < n2; idx += 256) {
            int j = i + 1 + idx / 15;
            int p = idx - (j - i - 1) * 15;
            const float2 v2 = *(const float2*)(cov + (size_t)(j * 30 + k) * 3840 + i * 30 + 2 * p);
            rowS[(j - j0) * 30 + 2 * p]     += v2.x;
            rowS[(j - j0) * 30 + 2 * p + 1] += v2.y;
        }
        __syncthreads();
        int t_st = i & 15;
        int nOct = W >> 3;
        for (int it = tid; it < nOct * 30; it += 256) {
            int oct = it / 30, l = it - oct * 30;
            int j = j0 + oct * 8;
            int s = j >> 4, kq = (j >> 3) & 1;
            int q = k * 30 + l, qt = q >> 5, l31 = q & 31;
            int kz, slot;
            if (g < 4) { kz = g;     slot = s - g; }
            else       { kz = 7 - g; slot = s + 1; }
            f16 vals[8];
#pragma unroll
            for (int d = 0; d < 8; ++d) vals[d] = (f16)rowS[(j + d - j0) * 30 + l];
            f16* dst = B5 + ((((size_t)(qt * 4 + kz) * 16 + t_st) * 9 + slot) << 9)
                          + (kq * 32 + l31) * 8;
            *(uint4*)dst = *(uint4*)vals;
        }
        return;
    }
    b -= PERM_BLKS;
    if (b < XC1_BLKS) {                           // Xh [v][r]
        int t = b * 256 + tid;
        int v = t & 2047, rc = t >> 11;
        f16 vals[8];
#pragma unroll
        for (int d = 0; d < 8; ++d) {
            float x = (v < NV) ? Xi[(rc * 8 + d) * NV + v] : 0.f;
            vals[d] = (f16)x;
        }
        *(uint4*)(Xh + (size_t)v * 128 + rc * 8) = *(uint4*)vals;
        return;
    }
    b -= XC1_BLKS;
    if (b < ZERO_BLKS) {
        size_t idx = ((size_t)b * 256 + tid) * 4;
        if (idx < (size_t)NV * QQ) {
            unsigned rem = (unsigned)(idx % QQ);
            float4 zv;
            zv.x = (rem == 0u)   ? 0.5f : 0.f;
            zv.y = (rem == 960u) ? 0.5f : 0.f;
            zv.z = (rem == 959u) ? 0.5f : 0.f;
            zv.w = (rem == 958u) ? 0.5f : 0.f;
            *(float4*)(oc + idx) = zv;
        }
        return;
    }
    b -= ZERO_BLKS;
    int t2 = b * 256 + tid;
    int c = t2 >> 11, v = t2 & 2047;
    if (v >= NV || c >= KKOUT) return;
    if (c == 0) { outm[(size_t)v * KKOUT] = Cmu[v]; return; }
    float acc = 0.f;
    const float* w = Wm + (c - 1);
#pragma unroll 8
    for (int i = 0; i < RR; ++i)
        acc = fmaf(Xi[i * NV + v], w[i * KM1], acc);
    outm[(size_t)v * KKOUT + c] = acc;
}

// ---------------------------------------------------------------------------
// Stage one 9216B stage into LDS. Wave w stages its own 2304B quarter as
// three chunks of HW-VERIFIED widths only: {16B,16B,4B} x 64 lanes
// (= 1024+1024+256 B). Uniform 3 VMEM issues per wave per stage -> clean
// per-wave vmcnt counting. Global src per-lane; LDS dst wave-uniform base
// (HW writes lane i at dst + i*size) -> exact linear copy of the stage.
// ---------------------------------------------------------------------------
__device__ __forceinline__ void stage_issue(const f16* gs, f16* ls, int w, int lane) {
    const f16* g = gs + w * 1152;                 // wave's 2304B segment
    f16* l = ls + w * 1152;
    __builtin_amdgcn_global_load_lds(
        (const __attribute__((address_space(1))) unsigned int*)(const void*)(g + lane * 8),
        (__attribute__((address_space(3))) unsigned int*)(void*)(l),
        16, 0, 0);
    __builtin_amdgcn_global_load_lds(
        (const __attribute__((address_space(1))) unsigned int*)(const void*)(g + 512 + lane * 8),
        (__attribute__((address_space(3))) unsigned int*)(void*)(l + 512),
        16, 0, 0);
    __builtin_amdgcn_global_load_lds(
        (const __attribute__((address_space(1))) unsigned int*)(const void*)(g + 1024 + lane * 2),
        (__attribute__((address_space(3))) unsigned int*)(void*)(l + 1024),
        4, 0, 0);
}

// ---------------------------------------------------------------------------
// one stage of one kz-section: 9 slots x 2 fm MFMAs.  KZ, T compile-time.
// B frags read from LDS (lb = buffer base + lane*8): 9x ds_read_b128,
// compiler interleaves with MFMAs via fine-grained lgkmcnt.
// role-A slots m: s = KZ+m, scalar xA = x[v, KZ*16+T];
// role-B slots m2: s = 7-KZ+m2, scalar xB = x[v, (7-KZ)*16+T].
// ---------------------------------------------------------------------------
template<int KZ, int T>
__device__ __forceinline__ void stage_compute(int l31, const f16* lb,
                                              const f16x8 (&xj)[2][8],
                                              f32x16 (&acc)[2]) {
    constexpr int NA = 8 - KZ, NB = 1 + KZ;
    f16x8 bv[9];
#pragma unroll
    for (int m = 0; m < 9; ++m)
        bv[m] = *(const f16x8*)(lb + m * 512);
    const int srcl = l31 + ((T >> 3) << 5);
    f16 xA[2], xB[2];
#pragma unroll
    for (int fm = 0; fm < 2; ++fm) {
        unsigned short ha = __builtin_bit_cast(unsigned short, (f16)xj[fm][KZ][T & 7]);
        unsigned short hb = __builtin_bit_cast(unsigned short, (f16)xj[fm][7 - KZ][T & 7]);
        int pa = __shfl((int)ha, srcl, 64);
        int pb = __shfl((int)hb, srcl, 64);
        xA[fm] = __builtin_bit_cast(f16, (unsigned short)pa);
        xB[fm] = __builtin_bit_cast(f16, (unsigned short)pb);
    }
#pragma unroll
    for (int m = 0; m < NA; ++m)
#pragma unroll
        for (int fm = 0; fm < 2; ++fm)
            acc[fm] = __builtin_amdgcn_mfma_f32_32x32x16_f16(xj[fm][KZ + m] * xA[fm], bv[m], acc[fm], 0, 0, 0);
#pragma unroll
    for (int m2 = 0; m2 < NB; ++m2)
#pragma unroll
        for (int fm = 0; fm < 2; ++fm)
            acc[fm] = __builtin_amdgcn_mfma_f32_32x32x16_f16(xj[fm][7 - KZ + m2] * xB[fm], bv[NA + m2], acc[fm], 0, 0, 0);
}

// ---------------------------------------------------------------------------
// Stage recursion, 32 local stages, 3 rolling LDS buffers, prefetch depth 2.
// Per stage: {FUSED asm: vmcnt(3) lgkmcnt(0); s_barrier} ; issue ST+2 ;
// compute ST.
// R5 lesson (NaN): wait and barrier as separate statements let hipcc hoist
// ds_reads between them (own chunks done, other waves' not -> garbage), and
// read-COMPLETION before barrier arrival wasn't guaranteed (rule #18: MFMAs
// + their lgkm waits can sink past asm). The single asm block with "memory"
// clobber pins all LDS/VMEM ops on both sides, and lgkmcnt(0) BEFORE
// s_barrier drains this wave's ds_reads so post-barrier overwrites of
// buf[(ST+2)%3] (= buf[(ST-1)%3]) are safe. vmcnt never drains to 0 in-loop
// (T3/T4): stage ST+1's 3 loads stay in flight across the barrier.
// ---------------------------------------------------------------------------
template<int KZH, int ST>
struct Stage {
    static __device__ __forceinline__ void run(const f16* gs, f16* lbuf,
                                               const f16* lrd,
                                               const f16x8 (&xj)[2][8],
                                               f32x16 (&acc)[2],
                                               int l31, int w, int lane) {
        if constexpr (ST == 31)
            asm volatile("s_waitcnt vmcnt(0) lgkmcnt(0)\ns_barrier" ::: "memory");
        else
            asm volatile("s_waitcnt vmcnt(3) lgkmcnt(0)\ns_barrier" ::: "memory");
        if constexpr (ST + 2 < 32)
            stage_issue(gs + (size_t)(ST + 2) * 4608, lbuf + ((ST + 2) % 3) * 4608, w, lane);
        stage_compute<KZH * 2 + (ST >> 4), ST & 15>(l31, lrd + (ST % 3) * 4608, xj, acc);
        Stage<KZH, ST + 1>::run(gs, lbuf, lrd, xj, acc, l31, w, lane);
    }
};
template<int KZH>
struct Stage<KZH, 32> {
    static __device__ __forceinline__ void run(const f16*, f16*, const f16*,
                                               const f16x8 (&)[2][8],
                                               f32x16 (&)[2], int, int, int) {}
};

// ---------------------------------------------------------------------------
// Half-kz GEMM, LDS-staged. Grid 464 = 29 qt x 8 y x 2 half; block = 4 waves
// x (64v x 32q), fm=2 -> 256 v. h=0: kz {0,1} (i 0..31 u 96..127); h=1:
// kz {2,3} (i 32..95); halves combine via atomicAdd onto prep's zero-init.
// R4 lesson: direct per-wave VMEM B-reads were L1-BW-bound (4 waves x same
// 1KB frags = 256 B/cy/CU demand vs ~64-85 ceiling -> MfmaUtil capped ~28%).
// Fix: stage each 9KB stage ONCE per block via global_load_lds (VMEM now
// ~64 B/cy/CU), broadcast via LDS (256 B/clk/CU).
// R0 lesson: __syncthreads would drain vmcnt -> raw s_barrier (inside the
// fused asm) + counted vmcnt(3) keeps prefetch in flight across barriers.
// XCD map unchanged (contiguous ~3.6-qt span per XCD, ~2.1MB L2-resident).
// ---------------------------------------------------------------------------
__launch_bounds__(256, 2)
__global__ void gemm9_kernel(const f16* __restrict__ B5,
                             const f16* __restrict__ Xh,
                             float* __restrict__ out_cov) {
    __shared__ f16 lbuf[3 * 4608];
    const int bid = blockIdx.x;
    const int p = (bid & 7) * 58 + (bid >> 3);   // 0..463
    const int qt = p >> 4;                        // 0..28
    const int r  = p & 15;
    const int y = r >> 1, h = r & 1;              // y 0..7, half 0..1
    const int tid = threadIdx.x, lane = tid & 63, w = tid >> 6;
    const int l31 = lane & 31, kq = lane >> 5;
    const int v0 = y * 256 + w * 64;
    const int vr = v0 + l31;

    // xj[fm][u]: x[vr+fm*32, u*16 + kq*8 + d], full s range
    f16x8 xj[2][8];
#pragma unroll
    for (int fm = 0; fm < 2; ++fm)
#pragma unroll
        for (int u = 0; u < 8; ++u)
            xj[fm][u] = *(const f16x8*)(Xh + (size_t)(vr + fm * 32) * 128 + u * 16 + kq * 8);

    const f16* gstage = B5 + ((size_t)qt * 64 + (size_t)h * 32) * 4608;
    const f16* lrd = lbuf + lane * 8;

    // prologue: stages 0 and 1 in flight (6 staging loads/wave outstanding;
    // stage-0's 3 are always older than stage-1's 3, so vmcnt(3) at ST=0
    // guarantees stage 0 landed regardless of where the xj loads schedule)
    stage_issue(gstage,        lbuf,        w, lane);
    stage_issue(gstage + 4608, lbuf + 4608, w, lane);

    f32x16 acc[2] = {};
    if (h == 0) Stage<0, 0>::run(gstage, lbuf, lrd, xj, acc, l31, w, lane);
    else        Stage<1, 0>::run(gstage, lbuf, lrd, xj, acc, l31, w, lane);

    // epilogue: 2-way partial sums -> atomicAdd onto zero-initialized cov.
    // C/D: col=l31 (q), row = 4*kq + (r&3) + 8*(r>>2) within fm's 32-v group.
    const int q = qt * 32 + l31;
    if (q >= NQ) return;
    const int kk = q / 30, ll = q - kk * 30;
    float* cb = out_cov + (kk + 1) * KKOUT + (ll + 1);
#pragma unroll
    for (int fm = 0; fm < 2; ++fm) {
        int vb = v0 + fm * 32 + 4 * kq;
#pragma unroll
        for (int rr = 0; rr < 16; ++rr) {
            int v = vb + (rr & 3) + 8 * (rr >> 2);
            if (v < NV) atomicAdd(cb + (size_t)v * QQ, acc[fm][rr]);
        }
    }
}

// ---------------------------------------------------------------------------
extern "C" void kernel_launch(void* const* d_in, const int* in_sizes, int n_in,
                              void* d_out, int out_size, void* d_ws, size_t ws_size,
                              hipStream_t stream) {
    const float* Xi  = (const float*)d_in[0];   // (128, 2000)
    const float* Wm  = (const float*)d_in[1];   // (3840, 1)
    const float* Cov = (const float*)d_in[2];   // (3840, 3840)
    const float* Cmu = (const float*)d_in[3];   // (2000, 1)
    float* out      = (float*)d_out;
    float* out_mean = out;                       // (2000, 31)
    float* out_cov  = out + COV_OFF;             // (2000, 31, 31)
    f16* B5 = (f16*)d_ws;
    f16* Xh = (f16*)((char*)d_ws + B5_BYTES);

    prep_kernel <<<PREP_GRID, 256, 0, stream>>>(Xi, Wm, Cov, Cmu, B5, Xh,
                                                out_mean, out_cov);
    gemm9_kernel<<<464, 256, 0, stream>>>(B5, Xh, out_cov);
}